// Round 12
// baseline (301.273 us; speedup 1.0000x reference)
//
#include <hip/hip_runtime.h>
#include <hip/hip_fp8.h>
#include <stdint.h>

#define K_DIM 4096
#define N_DIM 4096
#define NKB   32     // number of 128-wide K scale blocks

using f32x4 = __attribute__((ext_vector_type(4))) float;
using i32x4 = __attribute__((ext_vector_type(4))) int;
using i32x8 = __attribute__((ext_vector_type(8))) int;

#define GLOAD_LDS16(g, l)                                                      \
    __builtin_amdgcn_global_load_lds(                                          \
        (const __attribute__((address_space(1))) unsigned int*)(g),            \
        (__attribute__((address_space(3))) unsigned int*)(l), 16, 0, 0)
#define GLOAD_LDS4(g, l)                                                       \
    __builtin_amdgcn_global_load_lds(                                          \
        (const __attribute__((address_space(1))) unsigned int*)(g),            \
        (__attribute__((address_space(3))) unsigned int*)(l), 4, 0, 0)

__device__ __forceinline__ uint8_t to_fp8(float v) {
    __hip_fp8_e4m3 q(v);   // OCP e4m3fn, RNE saturating
    return (uint8_t)q.__x;
}

// ---------------- fused quant: act blocks first, then weight blocks ----------------
__global__ __launch_bounds__(256) void quant_kernel(
    const float* __restrict__ x, uint8_t* __restrict__ xq,
    float* __restrict__ saT,
    const float* __restrict__ w, uint8_t* __restrict__ wq,
    int M, int actBlocks)
{
    if ((int)blockIdx.x < actBlocks) {
        int gw   = blockIdx.x * 4 + (threadIdx.x >> 6);
        int lane = threadIdx.x & 63;
        int m    = gw >> 5;
        int kb   = gw & 31;
        size_t base = (size_t)m * K_DIM + kb * 128 + lane * 2;
        float2 v = *(const float2*)(x + base);
        float amax = fmaxf(fabsf(v.x), fabsf(v.y));
        #pragma unroll
        for (int o = 32; o >= 1; o >>= 1) amax = fmaxf(amax, __shfl_xor(amax, o));
        float s = amax / 448.0f;          // IEEE div, matches jnp exactly
        uchar2 q;
        q.x = to_fp8(v.x / s);
        q.y = to_fp8(v.y / s);
        *(uchar2*)(xq + base) = q;
        if (lane == 0) saT[(size_t)kb * M + m] = s;
    } else {
        size_t i = ((size_t)(blockIdx.x - actBlocks) * 256 + threadIdx.x) * 4;
        float4 v = *(const float4*)(w + i);
        uchar4 q;
        q.x = to_fp8(v.x); q.y = to_fp8(v.y); q.z = to_fp8(v.z); q.w = to_fp8(v.w);
        *(uchar4*)(wq + i) = q;
    }
}

// ---------------- ratio pre-kernel (verified R2/R8/R10): telescoping rescale factors ----------------
__global__ __launch_bounds__(256) void ratio_kernel(
    const float* __restrict__ saT, const float* __restrict__ ws,
    float* __restrict__ ra, float* __restrict__ rwr, int M)
{
    int idx = blockIdx.x * 256 + threadIdx.x;
    if (idx < 32 * M) {
        int sb = idx / M, m = idx - sb * M;
        float v = 1.0f;
        if (sb >= 1) v = saT[(size_t)(sb - 1) * M + m] / saT[(size_t)sb * M + m];
        ra[idx] = v;
    }
    if (idx < 32 * 32) {
        int sb = idx >> 5, nb = idx & 31;
        float v = 1.0f;
        if (sb >= 1) v = ws[nb * NKB + sb - 1] / ws[nb * NKB + sb];
        rwr[idx] = v;
    }
}

// ---------------- MX fp8 GEMM: 256x256 tile, BK=128, dbuf 2-phase (R6 schedule), 16 waves ----------------
// LDS per buffer: A 32K | B 32K | ratios 1K -> 66560 B; x2 = 133120 B (1 block/CU)
#define LSA(b) ((b) * 66560)
#define LSB(b) ((b) * 66560 + 32768)
#define LSS(b) ((b) * 66560 + 65536)

__global__ __launch_bounds__(1024, 1) void fp8_gemm_mx11(
    const uint8_t* __restrict__ Aq, const uint8_t* __restrict__ Bq,
    const float* __restrict__ saT, const float* __restrict__ ra,
    const float* __restrict__ rwr, const float* __restrict__ wscale,
    float* __restrict__ C, int M)
{
    __shared__ __align__(16) uint8_t lds[133120];

    const int t    = threadIdx.x;
    const int lane = t & 63;
    const int lr   = lane & 15;
    const int lk   = lane >> 4;          // 0..3 -> k sub-block of 32
    const int wid  = t >> 6;             // 0..15
    const int wm   = wid >> 2;           // 0..3 : wave row block (64 rows)
    const int wn   = wid & 3;            // 0..3 : wave col block (64 cols)

    const int gridN = N_DIM / 256;       // 16
    int nwg = (M / 256) * gridN;         // 512, %8==0
    int cpx = nwg >> 3;
    int bid = blockIdx.x;
    int swz = (bid & 7) * cpx + (bid >> 3);   // bijective XCD swizzle
    const int m0 = (swz / gridN) * 256;
    const int n0 = (swz % gridN) * 256;
    const int nb = (n0 >> 7) + (wn >> 1);     // global wscale row (0..31)

    // staging map (proven R3/R5/R6): thread t -> row srow, phys 16B chunk (t&7);
    // source logical chunk ((t&7)^(srow&7)) => phys_chunk = logical ^ (row&7)
    const int srow = t >> 3;                       // 0..127 per pass
    const int scol = ((t & 7) ^ (srow & 7)) * 16;
    const uint8_t* gA = Aq + (size_t)(m0 + srow) * K_DIM + scol;
    const uint8_t* gB = Bq + (size_t)(n0 + srow) * K_DIM + scol;
    const int ldst = t * 16;                       // 16 KB per pass (1024 thr)

    // fragment read swizzle: (row&7)==(lr&7)
    const int fsw = (lr & 7) << 4;
    const int c0  = (lk * 32) ^ fsw;

    // 4 staging passes per K-block: A rows 0-127,128-255; B rows 0-127,128-255
#define STAGE(buf, kbi) do {                                                   \
    size_t ko_ = (size_t)(kbi) * 128;                                          \
    _Pragma("unroll") for (int j = 0; j < 2; ++j) {                            \
        GLOAD_LDS16(gA + ko_ + (size_t)j * 128 * K_DIM,                        \
                    &lds[LSA(buf) + j * 16384 + ldst]);                        \
        GLOAD_LDS16(gB + ko_ + (size_t)j * 128 * K_DIM,                        \
                    &lds[LSB(buf) + j * 16384 + ldst]);                        \
    }                                                                          \
    if (wid < 4)                                                               \
        GLOAD_LDS4(ra + (size_t)(kbi) * M + m0 + wid * 64 + lane,              \
                   &lds[LSS(buf) + wid * 256 + lane * 4]);                     \
} while (0)

    f32x4 acc[4][4] = {};

    // ---- prologue: stage K-block 0 + ratio row 0 (all 1.0) into buf 0 ----
    STAGE(0, 0);
    asm volatile("s_waitcnt vmcnt(0)" ::: "memory");
    __builtin_amdgcn_s_barrier();

    #pragma unroll 2
    for (int kb = 0; kb < NKB; ++kb) {
        const int cur = kb & 1;
        // ---- issue next tile's staging FIRST (overlaps compute below) ----
        if (kb < NKB - 1) STAGE(cur ^ 1, kb + 1);

        const int aB = LSA(cur), bB = LSB(cur), sB = LSS(cur);
        const float rwc = rwr[kb * 32 + nb];      // wave-uniform ratio (1.0 at kb=0)

        // ---- fragments: 16x ds_read_b128 (A 4, B 4, 32B each) ----
        i32x8 af[4], bf[4];
        #pragma unroll
        for (int mi = 0; mi < 4; ++mi) {
            int rb = aB + (wm * 64 + mi * 16 + lr) * 128;
            i32x4 lo = *(const i32x4*)&lds[rb + c0];
            i32x4 hi = *(const i32x4*)&lds[rb + (c0 ^ 16)];
            af[mi] = __builtin_shufflevector(lo, hi, 0, 1, 2, 3, 4, 5, 6, 7);
        }
        #pragma unroll
        for (int ni = 0; ni < 4; ++ni) {
            int rb = bB + (wn * 64 + ni * 16 + lr) * 128;
            i32x4 lo = *(const i32x4*)&lds[rb + c0];
            i32x4 hi = *(const i32x4*)&lds[rb + (c0 ^ 16)];
            bf[ni] = __builtin_shufflevector(lo, hi, 0, 1, 2, 3, 4, 5, 6, 7);
        }

        // ---- telescoped rescale + in-place MFMA accumulate (proven R10) ----
        #pragma unroll
        for (int mi = 0; mi < 4; ++mi) {
            f32x4 ra4 = *(const f32x4*)&lds[sB + (wm * 64 + mi * 16 + lk * 4) * 4];
            f32x4 sc = ra4 * rwc;
            #pragma unroll
            for (int ni = 0; ni < 4; ++ni)
                acc[mi][ni] *= sc;
            #pragma unroll
            for (int ni = 0; ni < 4; ++ni)
                acc[mi][ni] =
                    __builtin_amdgcn_mfma_scale_f32_16x16x128_f8f6f4(
                        af[mi], bf[ni], acc[mi][ni],
                        0, 0, 0, 0x7F7F7F7F, 0, 0x7F7F7F7F);   // unit e8m0
        }

        // ---- single drain + barrier per K-block (R6 schedule) ----
        asm volatile("s_waitcnt vmcnt(0)" ::: "memory");
        __builtin_amdgcn_s_barrier();
    }
#undef STAGE

    // ---- epilogue: out = acc * s31[m] * ws[nb][31]; C/D layout col=lane&15, row=lk*4+j ----
    const float ws31 = wscale[nb * NKB + 31];
    #pragma unroll
    for (int mi = 0; mi < 4; ++mi) {
        f32x4 s31 = *(const f32x4*)(saT + (size_t)31 * M + m0 + wm * 64 + mi * 16 + lk * 4);
        f32x4 sc = s31 * ws31;
        #pragma unroll
        for (int j = 0; j < 4; ++j) {
            int m = m0 + wm * 64 + mi * 16 + lk * 4 + j;
            float* crow = C + (size_t)m * N_DIM + n0 + wn * 64;
            #pragma unroll
            for (int ni = 0; ni < 4; ++ni)
                crow[ni * 16 + lr] = acc[mi][ni][j] * sc[j];
        }
    }
}

extern "C" void kernel_launch(void* const* d_in, const int* in_sizes, int n_in,
                              void* d_out, int out_size, void* d_ws, size_t ws_size,
                              hipStream_t stream) {
    const float* x      = (const float*)d_in[0];
    const float* w      = (const float*)d_in[1];
    const float* wscale = (const float*)d_in[2];
    float* out = (float*)d_out;
    int M = in_sizes[0] / K_DIM;                  // 8192

    // workspace: xq [M*K] | wq [N*K] | saT [32*M] | ra [32*M] | rwr [32*32]
    uint8_t* xq  = (uint8_t*)d_ws;
    uint8_t* wq  = xq + (size_t)M * K_DIM;
    float*   saT = (float*)(wq + (size_t)N_DIM * K_DIM);
    float*   ra  = saT + (size_t)NKB * M;
    float*   rwr = ra + (size_t)NKB * M;

    int actBlocks = M * NKB / 4;
    int wBlocks   = (int)(((size_t)N_DIM * K_DIM) / 1024);
    quant_kernel<<<actBlocks + wBlocks, 256, 0, stream>>>(
        x, xq, saT, w, wq, M, actBlocks);
    ratio_kernel<<<(32 * M + 255) / 256, 256, 0, stream>>>(saT, wscale, ra, rwr, M);

    int nwg = (M / 256) * (N_DIM / 256);
    fp8_gemm_mx11<<<nwg, 1024, 0, stream>>>(xq, wq, saT, ra, rwr, wscale, out, M);
}

// Round 13
// 231.518 us; speedup vs baseline: 1.3013x; 1.3013x over previous
//
#include <hip/hip_runtime.h>
#include <hip/hip_fp8.h>
#include <stdint.h>

#define K_DIM 4096
#define N_DIM 4096
#define NKB   32     // number of 128-wide K scale blocks

using f32x4 = __attribute__((ext_vector_type(4))) float;
using i32x4 = __attribute__((ext_vector_type(4))) int;
using i32x8 = __attribute__((ext_vector_type(8))) int;

#define GLOAD_LDS16(g, l)                                                      \
    __builtin_amdgcn_global_load_lds(                                          \
        (const __attribute__((address_space(1))) unsigned int*)(g),            \
        (__attribute__((address_space(3))) unsigned int*)(l), 16, 0, 0)
#define GLOAD_LDS4(g, l)                                                       \
    __builtin_amdgcn_global_load_lds(                                          \
        (const __attribute__((address_space(1))) unsigned int*)(g),            \
        (__attribute__((address_space(3))) unsigned int*)(l), 4, 0, 0)

__device__ __forceinline__ uint8_t to_fp8(float v) {
    __hip_fp8_e4m3 q(v);   // OCP e4m3fn, RNE saturating
    return (uint8_t)q.__x;
}

// ---------------- fused quant: act blocks first, then weight blocks (R12, −9us vs split) ----------------
__global__ __launch_bounds__(256) void quant_kernel(
    const float* __restrict__ x, uint8_t* __restrict__ xq,
    float* __restrict__ saT,
    const float* __restrict__ w, uint8_t* __restrict__ wq,
    int M, int actBlocks)
{
    if ((int)blockIdx.x < actBlocks) {
        // activation quant: one wave per (m, kb); scales TRANSPOSED saT[kb][m]
        int gw   = blockIdx.x * 4 + (threadIdx.x >> 6);
        int lane = threadIdx.x & 63;
        int m    = gw >> 5;
        int kb   = gw & 31;
        size_t base = (size_t)m * K_DIM + kb * 128 + lane * 2;
        float2 v = *(const float2*)(x + base);
        float amax = fmaxf(fabsf(v.x), fabsf(v.y));
        #pragma unroll
        for (int o = 32; o >= 1; o >>= 1) amax = fmaxf(amax, __shfl_xor(amax, o));
        float s = amax / 448.0f;          // IEEE div, matches jnp exactly
        uchar2 q;
        q.x = to_fp8(v.x / s);
        q.y = to_fp8(v.y / s);
        *(uchar2*)(xq + base) = q;
        if (lane == 0) saT[(size_t)kb * M + m] = s;
    } else {
        size_t i = ((size_t)(blockIdx.x - actBlocks) * 256 + threadIdx.x) * 4;
        float4 v = *(const float4*)(w + i);
        uchar4 q;
        q.x = to_fp8(v.x); q.y = to_fp8(v.y); q.z = to_fp8(v.z); q.w = to_fp8(v.w);
        *(uchar4*)(wq + i) = q;
    }
}

// ---------------- MX fp8 GEMM: byte-exact R6 structure (best measured: 195.3 us) ----------------
// 256x256 tile, BK=128, double-buffered 2-phase, 8 waves of 128x64.
// LDS per buffer: A 32K | B 32K | scales 1K -> 66560 B; x2 = 133120 B (1 block/CU)
#define LSA(b) ((b) * 66560)
#define LSB(b) ((b) * 66560 + 32768)
#define LSS(b) ((b) * 66560 + 65536)

__global__ __launch_bounds__(512, 1) void fp8_gemm_mx4(
    const uint8_t* __restrict__ Aq, const uint8_t* __restrict__ Bq,
    const float* __restrict__ saT, const float* __restrict__ wscale,
    float* __restrict__ C, int M)
{
    __shared__ __align__(16) uint8_t lds[133120];

    const int t    = threadIdx.x;
    const int lane = t & 63;
    const int lr   = lane & 15;
    const int lk   = lane >> 4;          // 0..3 -> k sub-block of 32
    const int wid  = t >> 6;
    const int wm   = wid >> 2;           // 0..1 : wave row half (128 rows)
    const int wn   = wid & 3;            // 0..3 : wave col quarter (64 cols)

    const int gridN = N_DIM / 256;       // 16
    int nwg = (M / 256) * gridN;         // 512, %8==0
    int cpx = nwg >> 3;
    int bid = blockIdx.x;
    int swz = (bid & 7) * cpx + (bid >> 3);   // bijective XCD swizzle
    const int m0 = (swz / gridN) * 256;
    const int n0 = (swz % gridN) * 256;
    const int nbI = ((n0 >> 7) + (wn >> 1)) * NKB;  // wscale row for this wave

    // staging map (proven R3/R5/R6): thread t -> row srow, phys 16B chunk (t&7);
    // source logical chunk ((t&7)^(srow&7)) => phys_chunk = logical ^ (row&7)
    const int srow = t >> 3;                       // 0..63 per pass
    const int scol = ((t & 7) ^ (srow & 7)) * 16;
    const uint8_t* gA = Aq + (size_t)(m0 + srow) * K_DIM + scol;
    const uint8_t* gB = Bq + (size_t)(n0 + srow) * K_DIM + scol;
    const int ldst = t * 16;                       // 8 KB per pass

    // fragment read swizzle: (row&7)==(lr&7)
    const int fsw = (lr & 7) << 4;
    const int c0  = (lk * 32) ^ fsw;

#define STAGE(buf, kbi) do {                                                   \
    size_t ko_ = (size_t)(kbi) * 128;                                          \
    _Pragma("unroll") for (int j = 0; j < 4; ++j) {                            \
        GLOAD_LDS16(gA + ko_ + (size_t)j * 64 * K_DIM,                         \
                    &lds[LSA(buf) + j * 8192 + ldst]);                         \
        GLOAD_LDS16(gB + ko_ + (size_t)j * 64 * K_DIM,                         \
                    &lds[LSB(buf) + j * 8192 + ldst]);                         \
    }                                                                          \
    if (wid < 4)                                                               \
        GLOAD_LDS4(saT + (size_t)(kbi) * M + m0 + wid * 64 + lane,             \
                   &lds[LSS(buf) + wid * 256 + lane * 4]);                     \
} while (0)

    f32x4 acc[8][4] = {};
    const f32x4 vzero = {0.f, 0.f, 0.f, 0.f};

    // ---- prologue: stage K-block 0 into buf 0 ----
    STAGE(0, 0);
    asm volatile("s_waitcnt vmcnt(0)" ::: "memory");
    __builtin_amdgcn_s_barrier();

    #pragma unroll 2
    for (int kb = 0; kb < NKB; ++kb) {
        const int cur = kb & 1;
        // ---- issue next tile's staging FIRST (overlaps compute below) ----
        if (kb < NKB - 1) STAGE(cur ^ 1, kb + 1);

        const int aB = LSA(cur), bB = LSB(cur), sB = LSS(cur);
        const float rw = wscale[nbI + kb];        // wave-uniform scalar load

        // ---- B fragments once (4 x 32B), A per 64-row half (caps VGPR) ----
        i32x8 bf[4];
        #pragma unroll
        for (int ni = 0; ni < 4; ++ni) {
            int rb = bB + (wn * 64 + ni * 16 + lr) * 128;
            i32x4 lo = *(const i32x4*)&lds[rb + c0];
            i32x4 hi = *(const i32x4*)&lds[rb + (c0 ^ 16)];
            bf[ni] = __builtin_shufflevector(lo, hi, 0, 1, 2, 3, 4, 5, 6, 7);
        }
        #pragma unroll
        for (int mh = 0; mh < 2; ++mh) {
            i32x8 af[4];
            #pragma unroll
            for (int mi = 0; mi < 4; ++mi) {
                int rb = aB + (wm * 128 + mh * 64 + mi * 16 + lr) * 128;
                i32x4 lo = *(const i32x4*)&lds[rb + c0];
                i32x4 hi = *(const i32x4*)&lds[rb + (c0 ^ 16)];
                af[mi] = __builtin_shufflevector(lo, hi, 0, 1, 2, 3, 4, 5, 6, 7);
            }
            #pragma unroll
            for (int mi = 0; mi < 4; ++mi) {
                f32x4 s4 = *(const f32x4*)&lds[sB + (wm * 128 + mh * 64 + mi * 16 + lk * 4) * 4];
                f32x4 sc = s4 * rw;
                f32x4 bs[4];
                #pragma unroll
                for (int ni = 0; ni < 4; ++ni)
                    bs[ni] = __builtin_amdgcn_mfma_scale_f32_16x16x128_f8f6f4(
                        af[mi], bf[ni], vzero, 0, 0,
                        0, 0x7F7F7F7F, 0, 0x7F7F7F7F);   // unit e8m0 scales
                #pragma unroll
                for (int ni = 0; ni < 4; ++ni)
                    acc[mh * 4 + mi][ni] += bs[ni] * sc;
            }
        }

        // ---- single drain + barrier per K-block ----
        asm volatile("s_waitcnt vmcnt(0)" ::: "memory");
        __builtin_amdgcn_s_barrier();
    }
#undef STAGE

    // ---- epilogue: C/D layout col=lane&15, row=lk*4+j (verified R1/R3/R4/R6) ----
    #pragma unroll
    for (int q = 0; q < 8; ++q) {
        int mh = q >> 2, mi = q & 3;
        #pragma unroll
        for (int j = 0; j < 4; ++j) {
            int m = m0 + wm * 128 + mh * 64 + mi * 16 + lk * 4 + j;
            float* crow = C + (size_t)m * N_DIM + n0 + wn * 64;
            #pragma unroll
            for (int ni = 0; ni < 4; ++ni)
                crow[ni * 16 + lr] = acc[q][ni][j];
        }
    }
}

extern "C" void kernel_launch(void* const* d_in, const int* in_sizes, int n_in,
                              void* d_out, int out_size, void* d_ws, size_t ws_size,
                              hipStream_t stream) {
    const float* x      = (const float*)d_in[0];
    const float* w      = (const float*)d_in[1];
    const float* wscale = (const float*)d_in[2];
    float* out = (float*)d_out;
    int M = in_sizes[0] / K_DIM;                  // 8192

    // workspace: xq [M*K] | wq [N*K] | saT [32*M]
    uint8_t* xq  = (uint8_t*)d_ws;
    uint8_t* wq  = xq + (size_t)M * K_DIM;
    float*   saT = (float*)(wq + (size_t)N_DIM * K_DIM);

    int actBlocks = M * NKB / 4;
    int wBlocks   = (int)(((size_t)N_DIM * K_DIM) / 1024);
    quant_kernel<<<actBlocks + wBlocks, 256, 0, stream>>>(
        x, xq, saT, w, wq, M, actBlocks);

    int nwg = (M / 256) * (N_DIM / 256);
    fp8_gemm_mx4<<<nwg, 512, 0, stream>>>(xq, wq, saT, wscale, out, M);
}